// Round 7
// baseline (633.090 us; speedup 1.0000x reference)
//
#include <hip/hip_runtime.h>
#include <math.h>

// FusionNeRF round 9:
//   - r8 post-mortem: pipeline is real (AGPR accs explain VGPR=84), occupancy
//     restored (32.6%), 555us. Remaining gap = latency exposure: depth-1
//     prefetch covers only 78cyc MFMA vs ~200-250cyc L2 weight latency.
//   - r9: depth-2 WEIGHT prefetch (wa[3][4] triple-buffer, steady wait
//     vmcnt(8) lgkmcnt(4)). LDS acts stay depth-1 (register budget: ~100 arch
//     VGPR + 64 AGPR fits the 3-wave unified-file cap; depth-2 acts would not).
//     Layers remain SELF-CONTAINED (drain (0,0) at last k-step; no in-flight
//     asm load ever crosses plain-C code -> r7 clobber impossible).

#define RAYS 2048
#define SAMP 128
#define MTOT (RAYS * SAMP)
#define HD   256
#define BM   64              // samples per block
#define ES   136             // enc LDS stride (bf16), Kpad=128 (+8 pad, 272B rows)
#define HS   264             // hidden LDS stride (bf16), 256 (+8 pad, 528B rows)

// output float offsets
#define OUT_RGB   0
#define OUT_DEPTH 6144
#define OUT_W     8192
#define OUT_SW    270336
#define OUT_DW    532480

// bf16 weight workspace offsets (elements)
#define SW0 0
#define SW1 32768
#define SW2 98304
#define SW3 163840
#define SW4 229376
#define DW0 233472
#define DW1 266240
#define DW2 331776
#define DW3 397312
#define DW4 462848
#define WTOT 466944

typedef __attribute__((ext_vector_type(8))) short short8;
typedef __attribute__((ext_vector_type(4))) float f32x4;
typedef __attribute__((ext_vector_type(2))) unsigned int uint2v;

__device__ __forceinline__ float sigm(float x) { return 1.0f / (1.0f + expf(-x)); }

__device__ __forceinline__ short f2bf(float f) {   // RNE fp32 -> bf16
    union { float f; unsigned u; } v; v.f = f;
    unsigned r = v.u + 0x7fffu + ((v.u >> 16) & 1u);
    return (short)(r >> 16);
}

// Unmovable memory ops (volatile asm). Counted waits + sched_barrier(0) (rule #18).
#define GLB_LOAD(dst, ptr, imm) \
    asm volatile("global_load_dwordx4 %0, %1, off offset:%c2" \
                 : "=v"(dst) : "v"(ptr), "n"(imm))
#define LDS_READ(dst, addr, imm) \
    asm volatile("ds_read_b128 %0, %1 offset:%c2" \
                 : "=v"(dst) : "v"(addr), "n"(imm))
#define WAITCNT(vm, lg) do { \
    asm volatile("s_waitcnt vmcnt(%c0) lgkmcnt(%c1)" :: "n"(vm), "n"(lg)); \
    __builtin_amdgcn_sched_barrier(0); } while (0)

// Barrier with LDS drain only (validated r5/r8).
__device__ __forceinline__ void bar_lgkm() {
    __builtin_amdgcn_sched_barrier(0);
    asm volatile("s_waitcnt lgkmcnt(0)\n\ts_barrier" ::: "memory");
    __builtin_amdgcn_sched_barrier(0);
}
// Ordering-only barrier (all reads already drained via counted waits).
__device__ __forceinline__ void bar_only() {
    __builtin_amdgcn_sched_barrier(0);
    asm volatile("s_barrier" ::: "memory");
    __builtin_amdgcn_sched_barrier(0);
}

// ---------------- weight prep: W[K][N] fp32 -> Wt[Npad][Kpad] bf16 ----------------
__device__ __forceinline__ void conv1(const float* __restrict__ src, short* __restrict__ dst,
                                      int local, int K, int N, int Kpad) {
    const int n = local / Kpad, k = local - n * Kpad;
    const float v = (k < K && n < N) ? src[k * N + n] : 0.0f;
    dst[local] = f2bf(v);
}

__global__ __launch_bounds__(256)
void prep_weights(const float* sW0, const float* sW1, const float* sW2,
                  const float* sW3, const float* sW4,
                  const float* dW0, const float* dW1, const float* dW2,
                  const float* dW3, const float* dW4, short* __restrict__ dst)
{
    const int idx = blockIdx.x * 256 + threadIdx.x;
    if (idx >= WTOT) return;
    if      (idx < SW1) conv1(sW0, dst + SW0, idx - SW0,  90, 256, 128);
    else if (idx < SW2) conv1(sW1, dst + SW1, idx - SW1, 256, 256, 256);
    else if (idx < SW3) conv1(sW2, dst + SW2, idx - SW2, 256, 256, 256);
    else if (idx < SW4) conv1(sW3, dst + SW3, idx - SW3, 256, 256, 256);
    else if (idx < DW0) conv1(sW4, dst + SW4, idx - SW4, 256,   4, 256);
    else if (idx < DW1) conv1(dW0, dst + DW0, idx - DW0,  99, 256, 128);
    else if (idx < DW2) conv1(dW1, dst + DW1, idx - DW1, 256, 256, 256);
    else if (idx < DW3) conv1(dW2, dst + DW2, idx - DW2, 256, 256, 256);
    else if (idx < DW4) conv1(dW3, dst + DW3, idx - DW3, 256, 256, 256);
    else                conv1(dW4, dst + DW4, idx - DW4, 256,   5, 256);
}

// ---------------- MFMA dense layer: self-contained, depth-2 weight pipeline -----
// A-operand = weights Wt[256][K] (global, L2-hot), B-operand = acts [64][AS] (LDS).
// Entry:  issue W0,W1,W2 (12 GLB) + A0,A1 (8 LDS); wait (8,4)  -> k0 ready.
// Steady (1 <= kk <= KSTEPS-3): issue W(kk+2), A(kk+1); wait (8,4).
// kk == KSTEPS-2: issue A(kk+1); wait (4,4).
// kk == KSTEPS-1: wait (0,0) — layer fully drained, nothing crosses plain-C.
template <int KSTEPS, bool RELU, int AS>
__device__ __forceinline__ void layer256(const short* A,
                                         const short* __restrict__ Wt,
                                         const float* __restrict__ bias,
                                         short* O, int Os, int tid)
{
    const int w = tid >> 6, lane = tid & 63, qq = lane >> 4, col = lane & 15;
    constexpr int K = KSTEPS * 32;
    static_assert(KSTEPS >= 4, "pipeline depth assumes KSTEPS >= 4");

    const short* wp0 = Wt + (size_t)(w * 64 +  0 + col) * K + qq * 8;
    const short* wp1 = Wt + (size_t)(w * 64 + 16 + col) * K + qq * 8;
    const short* wp2 = Wt + (size_t)(w * 64 + 32 + col) * K + qq * 8;
    const short* wp3 = Wt + (size_t)(w * 64 + 48 + col) * K + qq * 8;
    // LDS byte address (generic shared addr: low 32 bits are the LDS offset)
    const unsigned ab = (unsigned)(size_t)(const void*)A + (unsigned)((col * AS + qq * 8) * 2);

    short8 wa[3][4], ba[2][4];   // all indices compile-time after full unroll

    // entry: weights k0,k1,k2 (longest latency first), then acts k0,k1
    GLB_LOAD(wa[0][0], wp0, 0);
    GLB_LOAD(wa[0][1], wp1, 0);
    GLB_LOAD(wa[0][2], wp2, 0);
    GLB_LOAD(wa[0][3], wp3, 0);
    GLB_LOAD(wa[1][0], wp0, 64);
    GLB_LOAD(wa[1][1], wp1, 64);
    GLB_LOAD(wa[1][2], wp2, 64);
    GLB_LOAD(wa[1][3], wp3, 64);
    GLB_LOAD(wa[2][0], wp0, 128);
    GLB_LOAD(wa[2][1], wp1, 128);
    GLB_LOAD(wa[2][2], wp2, 128);
    GLB_LOAD(wa[2][3], wp3, 128);
    LDS_READ(ba[0][0], ab, (0 * 16 * AS) * 2);
    LDS_READ(ba[0][1], ab, (1 * 16 * AS) * 2);
    LDS_READ(ba[0][2], ab, (2 * 16 * AS) * 2);
    LDS_READ(ba[0][3], ab, (3 * 16 * AS) * 2);
    LDS_READ(ba[1][0], ab, (0 * 16 * AS) * 2 + 64);
    LDS_READ(ba[1][1], ab, (1 * 16 * AS) * 2 + 64);
    LDS_READ(ba[1][2], ab, (2 * 16 * AS) * 2 + 64);
    LDS_READ(ba[1][3], ab, (3 * 16 * AS) * 2 + 64);
    WAITCNT(8, 4);   // k0 weights+acts ready; k1,k2 weights and k1 acts flying

    f32x4 acc[4][4];
#pragma unroll
    for (int ft = 0; ft < 4; ft++)
#pragma unroll
        for (int st = 0; st < 4; st++) acc[ft][st] = (f32x4)0.0f;

#pragma unroll
    for (int kk = 0; kk < KSTEPS; kk++) {
        const int c3 = kk % 3, c2 = kk & 1;
        if (kk >= 1 && kk <= KSTEPS - 3) {
            const int w3 = (kk + 2) % 3, a2 = (kk + 1) & 1;
            GLB_LOAD(wa[w3][0], wp0, (kk + 2) * 64);
            GLB_LOAD(wa[w3][1], wp1, (kk + 2) * 64);
            GLB_LOAD(wa[w3][2], wp2, (kk + 2) * 64);
            GLB_LOAD(wa[w3][3], wp3, (kk + 2) * 64);
            LDS_READ(ba[a2][0], ab, (0 * 16 * AS) * 2 + (kk + 1) * 64);
            LDS_READ(ba[a2][1], ab, (1 * 16 * AS) * 2 + (kk + 1) * 64);
            LDS_READ(ba[a2][2], ab, (2 * 16 * AS) * 2 + (kk + 1) * 64);
            LDS_READ(ba[a2][3], ab, (3 * 16 * AS) * 2 + (kk + 1) * 64);
            WAITCNT(8, 4);                 // W(kk)/A(kk) ready; 2 W-sets + 1 A-set flying
        } else if (kk == KSTEPS - 2) {
            const int a2 = (kk + 1) & 1;
            LDS_READ(ba[a2][0], ab, (0 * 16 * AS) * 2 + (kk + 1) * 64);
            LDS_READ(ba[a2][1], ab, (1 * 16 * AS) * 2 + (kk + 1) * 64);
            LDS_READ(ba[a2][2], ab, (2 * 16 * AS) * 2 + (kk + 1) * 64);
            LDS_READ(ba[a2][3], ab, (3 * 16 * AS) * 2 + (kk + 1) * 64);
            WAITCNT(4, 4);                 // W(kk)/A(kk) ready; last W + last A flying
        } else if (kk == KSTEPS - 1) {
            WAITCNT(0, 0);                 // drain: layer self-contained
        }
#pragma unroll
        for (int ft = 0; ft < 4; ft++)
#pragma unroll
            for (int st = 0; st < 4; st++)
                acc[ft][st] = __builtin_amdgcn_mfma_f32_16x16x32_bf16(
                    wa[c3][ft], ba[c2][st], acc[ft][st], 0, 0, 0);
    }

    bar_only();       // all waves done reading A (A may alias O)

#pragma unroll
    for (int ft = 0; ft < 4; ft++) {
        const f32x4 bv = *(const f32x4*)(bias + w * 64 + ft * 16 + qq * 4);
#pragma unroll
        for (int st = 0; st < 4; st++) {
            float v0 = acc[ft][st][0] + bv[0];
            float v1 = acc[ft][st][1] + bv[1];
            float v2 = acc[ft][st][2] + bv[2];
            float v3 = acc[ft][st][3] + bv[3];
            if (RELU) {
                v0 = fmaxf(v0, 0.0f); v1 = fmaxf(v1, 0.0f);
                v2 = fmaxf(v2, 0.0f); v3 = fmaxf(v3, 0.0f);
            }
            unsigned p0, p1;   // RNE pack, matches f2bf
            asm("v_cvt_pk_bf16_f32 %0, %1, %2" : "=v"(p0) : "v"(v0), "v"(v1));
            asm("v_cvt_pk_bf16_f32 %0, %1, %2" : "=v"(p1) : "v"(v2), "v"(v3));
            uint2v pk; pk[0] = p0; pk[1] = p1;
            *(uint2v*)(O + (size_t)(st * 16 + col) * Os + w * 64 + ft * 16 + qq * 4) = pk;
        }
    }
    bar_lgkm();   // O visible to next layer
}

// head (swapped): A-op = head weights Wt[16][256], B-op = acts of wave's 16 samples.
// Plain C — our asm queues are empty here (layers drain), compiler accounting exact.
template <int NV, int OS>
__device__ __forceinline__ void head256(const short* A, int As,
                                        const short* __restrict__ Wt,
                                        const float* __restrict__ bias,
                                        float* Out, int tid)
{
    const int w = tid >> 6, lane = tid & 63, qq = lane >> 4, col = lane & 15;
    f32x4 acc = (f32x4)0.0f;
#pragma unroll
    for (int kk = 0; kk < 8; kk++) {
        short8 a = *(const short8*)(Wt + col * 256 + kk * 32 + qq * 8);
        short8 b = *(const short8*)(A + (size_t)(w * 16 + col) * As + kk * 32 + qq * 8);
        acc = __builtin_amdgcn_mfma_f32_16x16x32_bf16(a, b, acc, 0, 0, 0);
    }
    const int s = w * 16 + col;
    if (qq == 0) {
#pragma unroll
        for (int i = 0; i < 4; i++) Out[s * OS + i] = acc[i] + bias[i];
    } else if (NV == 5 && qq == 1) {
        Out[s * OS + 4] = acc[0] + bias[4];
    }
}

__global__ __launch_bounds__(256, 3)
void nerf_mlp(const float* __restrict__ points, const float* __restrict__ dirsv,
              const float* __restrict__ timev, const short* __restrict__ wt,
              const float* __restrict__ sb0, const float* __restrict__ sb1,
              const float* __restrict__ sb2, const float* __restrict__ sb3,
              const float* __restrict__ sb4,
              const float* __restrict__ db0, const float* __restrict__ db1,
              const float* __restrict__ db2, const float* __restrict__ db3,
              const float* __restrict__ db4,
              float* __restrict__ o_sigma, float* __restrict__ o_r,
              float* __restrict__ o_g, float* __restrict__ o_b,
              float* __restrict__ o_bw)
{
    __shared__ __align__(16) short E[BM][ES];   // 17408 B
    __shared__ __align__(16) short Hb[BM][HS];  // 33792 B
    __shared__ float so[BM][4];                 //  1024 B
    __shared__ float dn[BM][5];                 //  1280 B -> 53504 B => 3 blocks/CU

    const int tid = threadIdx.x;
    const int m0  = blockIdx.x * BM;

    // ---- positional encoding -> E (bf16). sinf/cosf (no sincosf scratch). ----
    for (int idx = tid; idx < BM * 64; idx += 256) {
        const int s = idx >> 6, j = idx & 63, m = m0 + s;
        if (j < 46) {
            float x; int dsin, dcos;
            if (j < 30) {                       // pos: 10 bands x 3 coords
                const int l = j / 3, c = j - 3 * l;
                x = points[m * 3 + c] * (float)(1 << l);
                dsin = 3 + l * 6 + c; dcos = dsin + 3;
            } else if (j < 42) {                // dirs: 4 bands x 3 coords
                const int jj = j - 30, l = jj / 3, c = jj - 3 * l;
                x = dirsv[m * 3 + c] * (float)(1 << l);
                dsin = 66 + l * 6 + c; dcos = dsin + 3;
            } else {                            // time: 4 bands x 1
                const int l = j - 42;
                x = timev[m] * (float)(1 << l);
                dsin = 91 + 2 * l; dcos = dsin + 1;
            }
            E[s][dsin] = f2bf(sinf(x));
            E[s][dcos] = f2bf(cosf(x));
        } else {                                // passthroughs + zero pad
            int t = (j - 46) * 2;
#pragma unroll
            for (int u = 0; u < 2; u++, t++) {
                float v = 0.0f; int d;
                if (t < 3)       { d = t;        v = points[m * 3 + t]; }
                else if (t < 6)  { d = 60 + t;   v = dirsv[m * 3 + t - 3]; }  // 63..65
                else if (t == 6) { d = 90;       v = timev[m]; }
                else             { d = 92 + t; }                              // 99..127 = 0
                E[s][d] = f2bf(v);
            }
        }
    }
    bar_lgkm();

    // ---- static MLP ----
    layer256<4, true, ES>(&E[0][0],  wt + SW0, sb0, &Hb[0][0], HS, tid);
    layer256<8, true, HS>(&Hb[0][0], wt + SW1, sb1, &Hb[0][0], HS, tid);
    layer256<8, true, HS>(&Hb[0][0], wt + SW2, sb2, &Hb[0][0], HS, tid);
    layer256<8, true, HS>(&Hb[0][0], wt + SW3, sb3, &Hb[0][0], HS, tid);
    head256<4, 4>(&Hb[0][0], HS, wt + SW4, sb4, &so[0][0], tid);
    // (dynamic L0's bar_only orders these head reads of Hb vs its Hb overwrite)

    // ---- dynamic MLP ----
    layer256<4, true, ES>(&E[0][0],  wt + DW0, db0, &Hb[0][0], HS, tid);
    layer256<8, true, HS>(&Hb[0][0], wt + DW1, db1, &Hb[0][0], HS, tid);
    layer256<8, true, HS>(&Hb[0][0], wt + DW2, db2, &Hb[0][0], HS, tid);
    layer256<8, true, HS>(&Hb[0][0], wt + DW3, db3, &Hb[0][0], HS, tid);
    head256<5, 5>(&Hb[0][0], HS, wt + DW4, db4, &dn[0][0], tid);
    bar_lgkm();

    // ---- blend ----
    if (tid < BM) {
        const int s = tid, m = m0 + s;
        const float bw = sigm(dn[s][4]);
        const float sigma = (1.f - bw) * so[s][0] + bw * dn[s][0];
        const float r  = (1.f - bw) * sigm(so[s][1]) + bw * sigm(dn[s][1]);
        const float gg = (1.f - bw) * sigm(so[s][2]) + bw * sigm(dn[s][2]);
        const float bb = (1.f - bw) * sigm(so[s][3]) + bw * sigm(dn[s][3]);
        o_sigma[m] = sigma; o_r[m] = r; o_g[m] = gg; o_b[m] = bb; o_bw[m] = bw;
    }
}

// ---------------- compositing: one wave per ray, shuffle scan ----------------
__global__ __launch_bounds__(256)
void nerf_comp(const float* __restrict__ zv,
               const float* __restrict__ o_sigma, const float* __restrict__ o_r,
               const float* __restrict__ o_g, const float* __restrict__ o_b,
               const float* __restrict__ o_bw, float* __restrict__ out)
{
    const int ray  = blockIdx.x * 4 + (threadIdx.x >> 6);
    const int lane = threadIdx.x & 63;
    const int base = ray * SAMP;
    const int s0 = 2 * lane, s1 = s0 + 1;

    const float z0 = zv[base + s0];
    const float z1 = zv[base + s1];
    const float z2 = (lane < 63) ? zv[base + s1 + 1] : 0.0f;
    const float d0 = z1 - z0;
    const float d1 = (lane < 63) ? (z2 - z1) : 1e10f;

    const float sg0 = o_sigma[base + s0], sg1 = o_sigma[base + s1];
    const float a0 = 1.0f - expf(-sg0 * d0);
    const float a1 = 1.0f - expf(-sg1 * d1);
    const float f0 = 1.0f - a0 + 1e-10f;
    const float f1 = 1.0f - a1 + 1e-10f;

    float incl = f0 * f1;
#pragma unroll
    for (int dlt = 1; dlt < 64; dlt <<= 1) {
        const float t = __shfl_up(incl, dlt);
        if (lane >= dlt) incl *= t;
    }
    float ex = __shfl_up(incl, 1);
    if (lane == 0) ex = 1.0f;

    const float t0 = ex;
    const float t1 = ex * f0;
    const float w0 = a0 * t0, w1 = a1 * t1;

    const float bw0 = o_bw[base + s0], bw1 = o_bw[base + s1];
    out[OUT_W  + base + s0] = w0;               out[OUT_W  + base + s1] = w1;
    out[OUT_SW + base + s0] = (1.f - bw0) * w0; out[OUT_SW + base + s1] = (1.f - bw1) * w1;
    out[OUT_DW + base + s0] = bw0 * w0;         out[OUT_DW + base + s1] = bw1 * w1;

    float pr = w0 * o_r[base + s0] + w1 * o_r[base + s1];
    float pg = w0 * o_g[base + s0] + w1 * o_g[base + s1];
    float pb = w0 * o_b[base + s0] + w1 * o_b[base + s1];
    float pd = w0 * z0 + w1 * z1;
#pragma unroll
    for (int dlt = 32; dlt >= 1; dlt >>= 1) {
        pr += __shfl_down(pr, dlt);
        pg += __shfl_down(pg, dlt);
        pb += __shfl_down(pb, dlt);
        pd += __shfl_down(pd, dlt);
    }
    if (lane == 0) {
        out[OUT_RGB + ray * 3 + 0] = pr;
        out[OUT_RGB + ray * 3 + 1] = pg;
        out[OUT_RGB + ray * 3 + 2] = pb;
        out[OUT_DEPTH + ray] = pd;
    }
}

extern "C" void kernel_launch(void* const* d_in, const int* in_sizes, int n_in,
                              void* d_out, int out_size, void* d_ws, size_t ws_size,
                              hipStream_t stream)
{
    const float* points = (const float*)d_in[0];
    const float* dirsv  = (const float*)d_in[1];
    const float* zvals  = (const float*)d_in[2];
    const float* timev  = (const float*)d_in[3];

    const float *sW[5], *sb[5], *dW[5], *db[5];
    if (in_sizes[6] == 99 * 256) {
        for (int i = 0; i < 5; i++) {   // interleaved (sW_i, sb_i, dW_i, db_i)
            sW[i] = (const float*)d_in[4 + 4 * i + 0];
            sb[i] = (const float*)d_in[4 + 4 * i + 1];
            dW[i] = (const float*)d_in[4 + 4 * i + 2];
            db[i] = (const float*)d_in[4 + 4 * i + 3];
        }
    } else {
        for (int i = 0; i < 5; i++) {   // all static then all dynamic
            sW[i] = (const float*)d_in[4 + 2 * i + 0];
            sb[i] = (const float*)d_in[4 + 2 * i + 1];
            dW[i] = (const float*)d_in[14 + 2 * i + 0];
            db[i] = (const float*)d_in[14 + 2 * i + 1];
        }
    }

    // ws layout: bf16 weights (933888 B) then 5 fp32 per-sample arrays (1 MB each)
    short* wt = (short*)d_ws;
    float* ws = (float*)((char*)d_ws + (size_t)WTOT * 2);
    float* o_sigma = ws;
    float* o_r  = ws + (size_t)MTOT * 1;
    float* o_g  = ws + (size_t)MTOT * 2;
    float* o_b  = ws + (size_t)MTOT * 3;
    float* o_bw = ws + (size_t)MTOT * 4;

    prep_weights<<<(WTOT + 255) / 256, 256, 0, stream>>>(
        sW[0], sW[1], sW[2], sW[3], sW[4], dW[0], dW[1], dW[2], dW[3], dW[4], wt);

    nerf_mlp<<<MTOT / BM, 256, 0, stream>>>(points, dirsv, timev, wt,
        sb[0], sb[1], sb[2], sb[3], sb[4], db[0], db[1], db[2], db[3], db[4],
        o_sigma, o_r, o_g, o_b, o_bw);

    nerf_comp<<<RAYS / 4, 256, 0, stream>>>(zvals, o_sigma, o_r, o_g, o_b, o_bw,
                                            (float*)d_out);
}